// Round 4
// baseline (736.888 us; speedup 1.0000x reference)
//
#include <hip/hip_runtime.h>

// ---------------------------------------------------------------------------
// QuantumQLSTM: analytic collapse of the quantum circuit.
//   ang[g][b][n] = W_g[n,:256]·x + W_g[n,256:264]·hx + bias_g[n] + theta_g[n]
//   m[g][b][0]   = prod_{j=1..7} cos(ang[g][b][j])
//   m[g][b][n>0] = prod_{j=0..n} cos(ang[g][b][j])
// then a standard LSTM cell update.
// ---------------------------------------------------------------------------

#define BQ   512   // batch
#define TT   512   // timesteps
#define IND  256   // input dim
#define PRE_OFF 8704  // float offset of pre[] inside ws

// ws float layout:
//   [0, 8192)        Wt[d][gn]   (256 x 32)  x-part of W, transposed
//   [8192, 8448)     Wh[gn][j]   (32 x 8)    h-part of W
//   [8448, 8480)     C[gn]                    bias + theta
//   [8704, ...)      pre[bblk][t][b_loc][n][g]  (B*T*32 floats)
//                    bblk = b>>3, b_loc = b&7; per-(bblk,t) slab = 256 floats.

__global__ void prep_kernel(const float* __restrict__ Wf, const float* __restrict__ bf,
                            const float* __restrict__ Wi, const float* __restrict__ bi,
                            const float* __restrict__ Wg, const float* __restrict__ bg,
                            const float* __restrict__ Wo, const float* __restrict__ bo,
                            const float* __restrict__ th, float* __restrict__ wsf) {
    const float* W[4]    = {Wf, Wi, Wg, Wo};
    const float* bias[4] = {bf, bi, bg, bo};
    int d = threadIdx.x;  // 0..255
    for (int g = 0; g < 4; g++)
        for (int n = 0; n < 8; n++)
            wsf[d * 32 + g * 8 + n] = W[g][n * 264 + d];
    if (d < 32) {
        int g = d >> 3, n = d & 7;
        for (int j = 0; j < 8; j++)
            wsf[8192 + d * 8 + j] = W[g][n * 264 + 256 + j];
        wsf[8448 + d] = bias[g][n] + th[d];
    }
}

// R1-structure row-GEMM (best measured: 168us, VGPR=24, no AGPR churn).
// NO __launch_bounds__ (the (256,4) bound triggered AGPR-split churn in R3).
// Store: 8 contiguous float4 per thread (128B fully-dirtied lines, no write
// amplification), in the [bblk][t][b_loc][n][g] layout recur consumes.
__global__ void pre_gemm(const float* __restrict__ x,
                         const float* __restrict__ wsf,
                         float* __restrict__ pre) {
    const int bt = blockIdx.x * 256 + threadIdx.x;        // 0..262143
    const float4* xr = (const float4*)(x + (size_t)bt * IND);
    const float* cvec = wsf + 8448;
    float acc[32];
#pragma unroll
    for (int k = 0; k < 32; k++) acc[k] = cvec[k];
    for (int dq = 0; dq < 64; dq++) {
        float4 xv = xr[dq];
        const float* wr = wsf + dq * 128;   // uniform -> scalar loads
#pragma unroll
        for (int k = 0; k < 32; k++) acc[k] = fmaf(xv.x, wr[k], acc[k]);
#pragma unroll
        for (int k = 0; k < 32; k++) acc[k] = fmaf(xv.y, wr[32 + k], acc[k]);
#pragma unroll
        for (int k = 0; k < 32; k++) acc[k] = fmaf(xv.z, wr[64 + k], acc[k]);
#pragma unroll
        for (int k = 0; k < 32; k++) acc[k] = fmaf(xv.w, wr[96 + k], acc[k]);
    }
    const int b = bt >> 9, t = bt & 511;
    float* dst = pre + ((size_t)((b >> 3) * TT + t)) * 256 + (b & 7) * 32;
#pragma unroll
    for (int n = 0; n < 8; n++) {
        float4 v = make_float4(acc[n], acc[8 + n], acc[16 + n], acc[24 + n]);
        *(float4*)(dst + n * 4) = v;
    }
}

// --- DPP helpers (all VALU; no LDS pipe) -----------------------------------
template <int CTRL>
__device__ __forceinline__ float dpp0(float x) {
    // bound_ctrl=true: invalid source lanes produce 0 (callers guard).
    return __int_as_float(__builtin_amdgcn_update_dpp(
        0, __float_as_int(x), CTRL, 0xF, 0xF, true));
}
#define QP_X1 0xB1   // quad_perm [1,0,3,2]  : lane ^= 1
#define QP_X2 0x4E   // quad_perm [2,3,0,1]  : lane ^= 2
#define QP_X3 0x1B   // quad_perm [3,2,1,0]  : lane ^= 3
#define HMIR  0x141  // row_half_mirror      : lane ^= 7
#define SHR1  0x111
#define SHR2  0x112
#define SHR4  0x114
#define SHL7  0x107

// recur v2: lane = b_loc*8 + n (8 batches per wave64). Each lane computes all
// 4 gates of its qubit n. Cross-lane ops are exclusively DPP:
//  - prefix scan over qubits: row_shr 1/2/4 (8-aligned groups stay in-row)
//  - m0 (prod of c_1..c_7): XOR-butterfly product (qp1, qp2, half_mirror)
//  - h-dot: hx_j gathered by XOR masks {0..3}=quad_perm, {4..7}=hmir+quad_perm
// pre[] float4 per lane per step, prefetched 4 steps (~1300 cy) ahead.
__global__ __launch_bounds__(64, 1) void recur(const float* __restrict__ wsf,
                                               float* __restrict__ out) {
    const int lane  = threadIdx.x;
    const int n     = lane & 7;
    const int b     = blockIdx.x * 8 + (lane >> 3);
    const float L2E = 1.4426950408889634f;

    // w[g][k] pairs with H[k] below; H[k] carries hx_{n ^ msk[k]}.
    const int msk[8] = {0, 1, 2, 3, 7, 6, 5, 4};
    float w[4][8];
#pragma unroll
    for (int g = 0; g < 4; g++)
#pragma unroll
        for (int k = 0; k < 8; k++)
            w[g][k] = wsf[8192 + (g * 8 + n) * 8 + (n ^ msk[k])];

    const float4* pp = (const float4*)(wsf + PRE_OFF)
                     + (size_t)blockIdx.x * TT * 64 + lane;

    float hx = 0.0f, cx = 0.0f;
    float4 buf[4];
#pragma unroll
    for (int i = 0; i < 4; i++) buf[i] = pp[(size_t)i * 64];

    float* outp = out + (size_t)b * TT * 8 + n;

    for (int t = 0; t < TT; t++) {
        float4 pv = buf[t & 3];
        if (t + 4 < TT) buf[t & 3] = pp[(size_t)(t + 4) * 64];

        // gather hx_{n^m} for all 8 masks — pure DPP
        float hm = dpp0<HMIR>(hx);
        float H[8];
        H[0] = hx;             H[1] = dpp0<QP_X1>(hx);
        H[2] = dpp0<QP_X2>(hx); H[3] = dpp0<QP_X3>(hx);
        H[4] = hm;             H[5] = dpp0<QP_X1>(hm);
        H[6] = dpp0<QP_X2>(hm); H[7] = dpp0<QP_X3>(hm);

        float ang[4] = {pv.x, pv.y, pv.z, pv.w};
#pragma unroll
        for (int g = 0; g < 4; g++)
#pragma unroll
            for (int k = 0; k < 8; k++)
                ang[g] = fmaf(w[g][k], H[k], ang[g]);

        float m[4];
#pragma unroll
        for (int g = 0; g < 4; g++) {
            float c = __cosf(ang[g]);
            // inclusive scan T_n = prod_{0..n} c_j  (guards keep groups separate)
            float T = c;
            { float v = dpp0<SHR1>(T); T = (n >= 1) ? T * v : T; }
            { float v = dpp0<SHR2>(T); T = (n >= 2) ? T * v : T; }
            { float v = dpp0<SHR4>(T); T = (n >= 4) ? T * v : T; }
            // full product of e (c with c_0 -> 1): butterfly, result in all lanes
            float e = (n == 0) ? 1.0f : c;
            float r = e * dpp0<QP_X1>(e);
            r = r * dpp0<QP_X2>(r);
            r = r * dpp0<HMIR>(r);   // quad-uniform => XOR7 == XOR4
            m[g] = (n == 0) ? r : T;
        }

        // f,i,o: sigmoid; g: tanh = 2*sigmoid(2m)-1
        float f  = __builtin_amdgcn_rcpf(1.0f + __builtin_amdgcn_exp2f(m[0] * (-L2E)));
        float iv = __builtin_amdgcn_rcpf(1.0f + __builtin_amdgcn_exp2f(m[1] * (-L2E)));
        float gv = fmaf(2.0f, __builtin_amdgcn_rcpf(1.0f + __builtin_amdgcn_exp2f(m[2] * (-2.0f * L2E))), -1.0f);
        float ov = __builtin_amdgcn_rcpf(1.0f + __builtin_amdgcn_exp2f(m[3] * (-L2E)));

        cx = fmaf(f, cx, iv * gv);
        float t2 = __builtin_amdgcn_exp2f(cx * (-2.0f * L2E));
        hx = ov * fmaf(2.0f, __builtin_amdgcn_rcpf(1.0f + t2), -1.0f);

        outp[(size_t)t * 8] = hx;
    }
    out[(size_t)BQ * TT * 8 + b * 8 + n]          = hx;
    out[(size_t)BQ * TT * 8 + BQ * 8 + b * 8 + n] = cx;
}

extern "C" void kernel_launch(void* const* d_in, const int* in_sizes, int n_in,
                              void* d_out, int out_size, void* d_ws, size_t ws_size,
                              hipStream_t stream) {
    const float* x  = (const float*)d_in[0];
    const float* Wf = (const float*)d_in[1];
    const float* bf = (const float*)d_in[2];
    const float* Wi = (const float*)d_in[3];
    const float* bi = (const float*)d_in[4];
    const float* Wg = (const float*)d_in[5];
    const float* bg = (const float*)d_in[6];
    const float* Wo = (const float*)d_in[7];
    const float* bo = (const float*)d_in[8];
    const float* th = (const float*)d_in[9];
    float* wsf = (float*)d_ws;
    float* out = (float*)d_out;

    prep_kernel<<<1, 256, 0, stream>>>(Wf, bf, Wi, bi, Wg, bg, Wo, bo, th, wsf);
    pre_gemm<<<(BQ * TT) / 256, 256, 0, stream>>>(x, wsf, wsf + PRE_OFF);
    recur<<<BQ / 8, 64, 0, stream>>>(wsf, out);
}